// Round 3
// baseline (278.481 us; speedup 1.0000x reference)
//
#include <hip/hip_runtime.h>
#include <stdint.h>

#define NUM_HEADS 12
#define HEAD_DIM 64
#define EMB 768
#define SEQ 4096
#define BATCH 2
#define ROWS (BATCH*SEQ)     // 8192
#define DQKV (3*EMB)         // 2304

typedef __attribute__((ext_vector_type(8))) __bf16 bf16x8;
typedef __attribute__((ext_vector_type(4))) float floatx4;

static __device__ __forceinline__ unsigned short f2bf(float f) {
  unsigned int u = __float_as_uint(f);
  u += 0x7FFFu + ((u >> 16) & 1u);          // round-to-nearest-even
  return (unsigned short)(u >> 16);
}

static __device__ __forceinline__ float bf2f(unsigned short h) {
  return __uint_as_float(((unsigned int)h) << 16);
}

// truncating pack: two fp32 -> bf16x2 dword {hi(b),hi(a)} — 1 v_perm, no adds
static __device__ __forceinline__ unsigned int pack_bf2_trunc(float a, float b) {
  return __builtin_amdgcn_perm(__float_as_uint(b), __float_as_uint(a), 0x07060302u);
}

static __device__ __forceinline__ void async_cp16(void* lds, const void* g) {
  __builtin_amdgcn_global_load_lds(
      (__attribute__((address_space(1))) void*)(g),
      (__attribute__((address_space(3))) void*)(lds), 16, 0, 0);
}

// key permutation within a 32-key group: PV lane (quad fq) reads its 8 keys
// {4fq+0..3, 16+4fq+0..3} as ONE contiguous 16B chunk (conflict-free b128).
static __device__ __forceinline__ int perm_key(int nn) {
  return (nn & ~31) | (((nn >> 2) & 3) * 8 + ((nn >> 4) & 1) * 4 + (nn & 3));
}

// ---------------- fp32 -> bf16 convert (x and w fused) ----------------
#define N4X (ROWS*EMB/4)
#define N4W (DQKV*EMB/4)
__global__ __launch_bounds__(256) void cvt2_kernel(
    const float* __restrict__ x, const float* __restrict__ w,
    unsigned short* __restrict__ xb, unsigned short* __restrict__ wb) {
  int i = blockIdx.x * blockDim.x + threadIdx.x;
  const float4* src;
  ushort4* dst;
  if (i < N4X) { src = (const float4*)x; dst = (ushort4*)xb; }
  else { i -= N4X; if (i >= N4W) return; src = (const float4*)w; dst = (ushort4*)wb; }
  float4 v = src[i];
  ushort4 o;
  o.x = f2bf(v.x); o.y = f2bf(v.y); o.z = f2bf(v.z); o.w = f2bf(v.w);
  dst[i] = o;
}

// ---------------- unified QKV projection GEMM (unchanged) --------
__global__ __launch_bounds__(256) void qkv_gemm_kernel(
    const unsigned short* __restrict__ xb, const unsigned short* __restrict__ wb,
    const float* __restrict__ bias,
    unsigned short* __restrict__ Qb, unsigned short* __restrict__ Kb,
    unsigned short* __restrict__ Vt) {
  __shared__ unsigned short As[128 * 64];
  __shared__ unsigned short Bs[128 * 64];
  const int t = threadIdx.x;
  const int lane = t & 63;
  const int w = t >> 6;
  const int wm = w >> 1, wn = w & 1;
  const int fr = lane & 15, fq = lane >> 4;
  const int fx = fr & 7;
  const int m0 = blockIdx.x * 128;
  const int n0 = blockIdx.y * 128;
  const int sel = n0 / EMB;       // 0=Q 1=K 2=V (block-uniform)
  const int lr = t >> 3;          // 0..31
  const int sc = t & 7;           // chunk col 0..7

  floatx4 acc[4][4];
#pragma unroll
  for (int i = 0; i < 4; ++i)
#pragma unroll
    for (int j = 0; j < 4; ++j) acc[i][j] = (floatx4)(0.0f);

  if (sel < 2) {
    for (int k0 = 0; k0 < EMB; k0 += 64) {
      __syncthreads();
#pragma unroll
      for (int i = 0; i < 4; ++i) {
        const int rr = i*32 + lr;
        const int cg = ((sc ^ (lr & 7)) * 8);
        async_cp16(&As[rr*64 + sc*8], &xb[(size_t)(m0 + rr)*EMB + k0 + cg]);
        async_cp16(&Bs[rr*64 + sc*8], &wb[(size_t)(n0 + rr)*EMB + k0 + cg]);
      }
      __syncthreads();
#pragma unroll
      for (int ks = 0; ks < 2; ++ks) {
        bf16x8 af[4], bfr[4];
#pragma unroll
        for (int i = 0; i < 4; ++i)
          af[i] = *(const bf16x8*)&As[(wm*64 + i*16 + fr)*64 + (((ks*4+fq) ^ fx)*8)];
#pragma unroll
        for (int j = 0; j < 4; ++j)
          bfr[j] = *(const bf16x8*)&Bs[(wn*64 + j*16 + fr)*64 + (((ks*4+fq) ^ fx)*8)];
#pragma unroll
        for (int i = 0; i < 4; ++i)
#pragma unroll
          for (int j = 0; j < 4; ++j)
            acc[i][j] = __builtin_amdgcn_mfma_f32_16x16x32_bf16(bfr[j], af[i], acc[i][j], 0, 0, 0);
      }
    }
    // D layout: row (feature) = j*16 + fq*4 + reg, col (x row) = i*16 + fr.
    const float qscale = 0.125f * 1.4426950408889634f;  // 1/sqrt(64)*log2(e)
    const float sc2 = (sel == 0) ? qscale : 1.0f;
    unsigned short* dst = (sel == 0) ? Qb : Kb;
#pragma unroll
    for (int i = 0; i < 4; ++i) {
      const int mr = m0 + wm*64 + i*16 + fr;      // x row
      const int b = mr / SEQ;
      const int nn = mr - b*SEQ;
#pragma unroll
      for (int j = 0; j < 4; ++j) {
        const int og = n0 + wn*64 + j*16 + fq*4;  // feature base (4 consecutive)
        const int oo = og - sel*EMB;
        const int hh = oo >> 6, dd = oo & 63;
        const float4 bv = *(const float4*)&bias[og];
        ushort4 pk;
        pk.x = f2bf((acc[i][j][0] + bv.x) * sc2);
        pk.y = f2bf((acc[i][j][1] + bv.y) * sc2);
        pk.z = f2bf((acc[i][j][2] + bv.z) * sc2);
        pk.w = f2bf((acc[i][j][3] + bv.w) * sc2);
        *(ushort4*)&dst[(((size_t)(b*NUM_HEADS + hh))*SEQ + nn)*HEAD_DIM + dd] = pk;
      }
    }
  } else {
    for (int k0 = 0; k0 < EMB; k0 += 64) {
      __syncthreads();
#pragma unroll
      for (int i = 0; i < 4; ++i) {
        const int rr = i*32 + lr;
        const int cg = ((sc ^ (lr & 7)) * 8);
        async_cp16(&As[rr*64 + sc*8], &xb[(size_t)(m0 + rr)*EMB + k0 + cg]);
        async_cp16(&Bs[rr*64 + sc*8], &wb[(size_t)(n0 + rr)*EMB + k0 + cg]);
      }
      __syncthreads();
#pragma unroll
      for (int ks = 0; ks < 2; ++ks) {
        bf16x8 af[4], bfr[4];
#pragma unroll
        for (int i = 0; i < 4; ++i)
          af[i] = *(const bf16x8*)&As[(wm*64 + i*16 + fr)*64 + (((ks*4+fq) ^ fx)*8)];
#pragma unroll
        for (int j = 0; j < 4; ++j)
          bfr[j] = *(const bf16x8*)&Bs[(wn*64 + j*16 + fr)*64 + (((ks*4+fq) ^ fx)*8)];
#pragma unroll
        for (int i = 0; i < 4; ++i)
#pragma unroll
          for (int j = 0; j < 4; ++j)
            acc[i][j] = __builtin_amdgcn_mfma_f32_16x16x32_bf16(af[i], bfr[j], acc[i][j], 0, 0, 0);
      }
    }
    // D layout: row (x row) = i*16 + fq*4 + reg, col (feature) = j*16 + fr.
#pragma unroll
    for (int i = 0; i < 4; ++i) {
      const int mr = m0 + wm*64 + i*16 + fq*4;    // x row base (4 consecutive)
      const int b = mr / SEQ;
      const int nn = perm_key(mr - b*SEQ);        // key-permuted position
#pragma unroll
      for (int j = 0; j < 4; ++j) {
        const int feat = n0 + wn*64 + j*16 + fr;
        const int oo = feat - 2*EMB;
        const int hh = oo >> 6, dd = oo & 63;
        const float bv = bias[feat];
        ushort4 pk;
        pk.x = f2bf(acc[i][j][0] + bv);
        pk.y = f2bf(acc[i][j][1] + bv);
        pk.z = f2bf(acc[i][j][2] + bv);
        pk.w = f2bf(acc[i][j][3] + bv);
        *(ushort4*)&Vt[(((size_t)(b*NUM_HEADS + hh))*HEAD_DIM + dd)*SEQ + nn] = pk;
      }
    }
  }
}

// ---------------- flash attention: split-K, 2 waves x 64 q-rows --------------
// grid (SEQ/128, BATCH*NUM_HEADS, 2): blockIdx.z = key-half. Each block does
// 128 q-rows x 2048 keys and writes UNNORMALIZED partial O (f32) + partial
// row-sum l; ln_kernel merges exactly: att = (O0+O1)/(l0+l1) (no running max in
// this softmax, so split is exact). Rationale (R2 measurement): 64q/wave is
// 1.61x more efficient per wave than 32q (half the LDS fragment traffic, 4
// independent g-streams), but non-split it only fields 1536 waves (4.8/CU,
// MfmaUtil 36%). Split-K doubles the grid back to 3072 waves (~10/CU resident,
// LDS-capped at 5 blocks/CU) while keeping the better per-wave structure.
#define NKH (SEQ/2)          // keys per half = 2048
#define NTH (NKH/64)         // 32 tiles per half
__global__ __launch_bounds__(128, 2) void attn_kernel(
    const unsigned short* __restrict__ Qb, const unsigned short* __restrict__ Kb,
    const unsigned short* __restrict__ Vt,
    float* __restrict__ Opart, float* __restrict__ lpart) {
  __shared__ unsigned short Ks[2][64 * 64];   // [buf][key][d], swizzled chunks
  __shared__ unsigned short Vs[2][64 * 64];   // [buf][d][perm key], swizzled
  const int t = threadIdx.x;
  const int lane = t & 63;
  const int w = t >> 6;                     // 0..1
  const int fr = lane & 15, fq = lane >> 4;
  const int fx = fr & 7;
  const int bh = blockIdx.y;
  const int half = blockIdx.z;
  const int kc0 = half * NKH;
  const int q0 = blockIdx.x * 128 + w * 64;

  // Q fragments (B-operand of S^T): per q-group g, rows q0+g*16+fr.
  bf16x8 aq[4][2];
#pragma unroll
  for (int g = 0; g < 4; ++g) {
    const size_t qoff = ((size_t)bh * SEQ + q0 + g*16 + fr) * HEAD_DIM;
    aq[g][0] = *(const bf16x8*)&Qb[qoff + fq*8];
    aq[g][1] = *(const bf16x8*)&Qb[qoff + 32 + fq*8];
  }

  union { unsigned int u[4]; bf16x8 b; } onesu;
  onesu.u[0] = onesu.u[1] = onesu.u[2] = onesu.u[3] = 0x3F803F80u;
  const bf16x8 onesb = onesu.b;

  floatx4 o[4][4];
  floatx4 lsum[4];
#pragma unroll
  for (int g = 0; g < 4; ++g) {
    lsum[g] = (floatx4)(0.f);
#pragma unroll
    for (int d = 0; d < 4; ++d) o[g][d] = (floatx4)(0.f);
  }

  const size_t kb = (size_t)bh * SEQ * HEAD_DIM;
  const size_t vb = (size_t)bh * HEAD_DIM * SEQ;

  // stage one 64-key tile: 8KB K + 8KB V = 1024 chunks / 128 thr = 8 cp16/thr
  auto stage = [&](int kc, int bi) {
#pragma unroll
    for (int i = 0; i < 4; ++i) {
      const int chunk = i*128 + t;
      const int r = chunk >> 3, c = chunk & 7;
      async_cp16(&Ks[bi][chunk*8], &Kb[kb + (size_t)(kc + r)*HEAD_DIM + ((c ^ (r&7))*8)]);
    }
#pragma unroll
    for (int i = 0; i < 4; ++i) {
      const int chunk = i*128 + t;
      const int r = chunk >> 3, c = chunk & 7;
      async_cp16(&Vs[bi][chunk*8], &Vt[vb + (size_t)r*SEQ + kc + ((c ^ (r&7))*8)]);
    }
  };

  // one 32-key chunk J of the current 64-key tile
  auto chunk_compute = [&](const unsigned short* ksp, const unsigned short* vsp,
                           int J) {
    // S^T fragments: 16 MFMAs off 4 ds_reads (k0/k1 shared across all 4 g)
    floatx4 z[4][2];
#pragma unroll
    for (int jj = 0; jj < 2; ++jj) {
      const int row = (J*2 + jj)*16 + fr;   // key row in tile
      bf16x8 k0 = *(const bf16x8*)&ksp[row*64 + ((fq ^ fx)*8)];
      bf16x8 k1 = *(const bf16x8*)&ksp[row*64 + (((fq+4) ^ fx)*8)];
#pragma unroll
      for (int g = 0; g < 4; ++g) {
        floatx4 a = (floatx4)(0.f);
        a = __builtin_amdgcn_mfma_f32_16x16x32_bf16(k0, aq[g][0], a, 0, 0, 0);
        a = __builtin_amdgcn_mfma_f32_16x16x32_bf16(k1, aq[g][1], a, 0, 0, 0);
        z[g][jj] = a;                       // S^T: key=16(2J+jj)+fq*4+r, q=fr
      }
    }
    // V fragments once per chunk, shared across g (4 ds_reads)
    bf16x8 vvb[4];
    const int vc = ((4*J + fq) ^ fx) * 8;
#pragma unroll
    for (int dt = 0; dt < 4; ++dt)
      vvb[dt] = *(const bf16x8*)&vsp[(dt*16 + fr)*64 + vc];
    // per-g softmax + lsum + PV: exp2 of g overlaps MFMAs of g-1
#pragma unroll
    for (int g = 0; g < 4; ++g) {
      float e0 = __builtin_amdgcn_exp2f(z[g][0][0]);
      float e1 = __builtin_amdgcn_exp2f(z[g][0][1]);
      float e2 = __builtin_amdgcn_exp2f(z[g][0][2]);
      float e3 = __builtin_amdgcn_exp2f(z[g][0][3]);
      float e4 = __builtin_amdgcn_exp2f(z[g][1][0]);
      float e5 = __builtin_amdgcn_exp2f(z[g][1][1]);
      float e6 = __builtin_amdgcn_exp2f(z[g][1][2]);
      float e7 = __builtin_amdgcn_exp2f(z[g][1][3]);
      union { unsigned int u[4]; bf16x8 b; } cv;
      cv.u[0] = pack_bf2_trunc(e0, e1);
      cv.u[1] = pack_bf2_trunc(e2, e3);
      cv.u[2] = pack_bf2_trunc(e4, e5);
      cv.u[3] = pack_bf2_trunc(e6, e7);
      const bf16x8 ap = cv.b;
      __builtin_amdgcn_s_setprio(1);
      lsum[g] = __builtin_amdgcn_mfma_f32_16x16x32_bf16(ap, onesb, lsum[g], 0, 0, 0);
#pragma unroll
      for (int dt = 0; dt < 4; ++dt)
        o[g][dt] = __builtin_amdgcn_mfma_f32_16x16x32_bf16(ap, vvb[dt], o[g][dt], 0, 0, 0);
      __builtin_amdgcn_s_setprio(0);
    }
  };

  // prologue: prefetch tiles 0 and 1, wait tile 0 only (tile 1 stays in flight)
  stage(kc0, 0);
  stage(kc0 + 64, 1);
  asm volatile("s_waitcnt vmcnt(8)" ::: "memory");
  __builtin_amdgcn_s_barrier();

  int cur = 0;
  for (int tt = 0; tt < NTH; ++tt) {
    const unsigned short* ksp = Ks[cur];
    const unsigned short* vsp = Vs[cur];
    chunk_compute(ksp, vsp, 0);
    chunk_compute(ksp, vsp, 1);
    if (tt == NTH - 1) break;
    __builtin_amdgcn_s_barrier();    // all waves done reading buf[cur]
    if (tt + 2 < NTH) {
      stage(kc0 + (tt + 2) * 64, cur);  // refill the buffer we just finished
      asm volatile("s_waitcnt vmcnt(8)" ::: "memory");  // tile tt+1 landed
    } else {
      asm volatile("s_waitcnt vmcnt(0)" ::: "memory");  // drain final tile
    }
    __builtin_amdgcn_s_barrier();    // tile tt+1 visible to all waves
    cur ^= 1;
  }

  // epilogue: write unnormalized partial O (f32) + partial row-sum l
  const size_t pb = (size_t)(half * BATCH * NUM_HEADS + bh);
  const size_t obase = pb * SEQ * HEAD_DIM;
  const size_t lbase = pb * SEQ;
#pragma unroll
  for (int g = 0; g < 4; ++g) {
#pragma unroll
    for (int r4 = 0; r4 < 4; ++r4) {
      const int q = q0 + g*16 + fq*4 + r4;
      float* op = &Opart[obase + (size_t)q * HEAD_DIM];
#pragma unroll
      for (int dt = 0; dt < 4; ++dt)
        op[dt*16 + fr] = o[g][dt][r4];
      if (fr == 0) lpart[lbase + q] = lsum[g][r4];
    }
  }
}

// ---------- residual + split-K merge + LayerNorm: one wave per row ----------
__global__ __launch_bounds__(256) void ln_kernel(
    const float* __restrict__ x,
    const float* __restrict__ Opart, const float* __restrict__ lpart,
    const float* __restrict__ gamma, const float* __restrict__ beta,
    float* __restrict__ out) {
  const int row = blockIdx.x * 4 + (threadIdx.x >> 6);  // global row b*SEQ+n
  const int lane = threadIdx.x & 63;
  const int b = row >> 12;              // / SEQ
  const int n = row & (SEQ - 1);
  const size_t base = (size_t)row * EMB;
  const size_t HSTRIDE = (size_t)BATCH * NUM_HEADS * SEQ;   // half stride (l)
  const size_t HOSTRIDE = HSTRIDE * HEAD_DIM;               // half stride (O)
  float4 v[3];
  float s = 0.f, s2 = 0.f;
#pragma unroll
  for (int k = 0; k < 3; ++k) {
    const int c = lane*4 + k*256;
    const int h = c >> 6, d4 = c & 63;
    const size_t oi = (((size_t)(b*NUM_HEADS + h))*SEQ + n)*HEAD_DIM + d4;
    const size_t li = ((size_t)(b*NUM_HEADS + h))*SEQ + n;
    const float4 p0 = *(const float4*)&Opart[oi];
    const float4 p1 = *(const float4*)&Opart[oi + HOSTRIDE];
    const float rl = 1.0f / (lpart[li] + lpart[li + HSTRIDE]);
    const float4 xv = *(const float4*)&x[base + c];
    v[k].x = xv.x + (p0.x + p1.x) * rl;
    v[k].y = xv.y + (p0.y + p1.y) * rl;
    v[k].z = xv.z + (p0.z + p1.z) * rl;
    v[k].w = xv.w + (p0.w + p1.w) * rl;
    s  += (v[k].x + v[k].y) + (v[k].z + v[k].w);
    s2 += (v[k].x*v[k].x + v[k].y*v[k].y) + (v[k].z*v[k].z + v[k].w*v[k].w);
  }
#pragma unroll
  for (int off = 1; off < 64; off <<= 1) {
    s  += __shfl_xor(s,  off);
    s2 += __shfl_xor(s2, off);
  }
  const float mean = s * (1.0f / EMB);
  const float var  = s2 * (1.0f / EMB) - mean * mean;
  const float rstd = rsqrtf(var + 1e-5f);
#pragma unroll
  for (int k = 0; k < 3; ++k) {
    const int c = lane*4 + k*256;
    const float4 g4 = *(const float4*)&gamma[c];
    const float4 b4 = *(const float4*)&beta[c];
    float4 ov;
    ov.x = (v[k].x - mean) * rstd * g4.x + b4.x;
    ov.y = (v[k].y - mean) * rstd * g4.y + b4.y;
    ov.z = (v[k].z - mean) * rstd * g4.z + b4.z;
    ov.w = (v[k].w - mean) * rstd * g4.w + b4.w;
    *(float4*)&out[base + c] = ov;
  }
}

extern "C" void kernel_launch(void* const* d_in, const int* in_sizes, int n_in,
                              void* d_out, int out_size, void* d_ws, size_t ws_size,
                              hipStream_t stream) {
  const float* x      = (const float*)d_in[0];
  const float* w_qkv  = (const float*)d_in[1];
  const float* b_qkv  = (const float*)d_in[2];
  const float* gamma  = (const float*)d_in[3];
  const float* beta   = (const float*)d_in[4];
  float* out = (float*)d_out;

  unsigned short* xb = (unsigned short*)d_ws;                 // 8192*768 bf16
  unsigned short* wb = xb + (size_t)ROWS * EMB;               // 2304*768 bf16
  unsigned short* Qb = wb + (size_t)DQKV * EMB;               // [b,h,n,64] bf16 (scaled)
  unsigned short* Kb = Qb + (size_t)ROWS * EMB;               // [b,h,n,64] bf16
  unsigned short* Vt = Kb + (size_t)ROWS * EMB;               // [b,h,64,perm n] bf16
  float* Opart = (float*)(Vt + (size_t)ROWS * EMB);           // [2,b,h,n,64] f32
  float* lpart = Opart + (size_t)2 * ROWS * EMB;              // [2,b,h,n] f32

  cvt2_kernel<<<(N4X + N4W + 255)/256, 256, 0, stream>>>(x, w_qkv, xb, wb);
  qkv_gemm_kernel<<<dim3(ROWS/128, DQKV/128), 256, 0, stream>>>(xb, wb, b_qkv, Qb, Kb, Vt);
  attn_kernel<<<dim3(SEQ/128, BATCH*NUM_HEADS, 2), 128, 0, stream>>>(Qb, Kb, Vt, Opart, lpart);
  ln_kernel<<<ROWS/4, 256, 0, stream>>>(x, Opart, lpart, gamma, beta, out);
}

// Round 5
// 255.449 us; speedup vs baseline: 1.0902x; 1.0902x over previous
//
#include <hip/hip_runtime.h>
#include <stdint.h>

#define NUM_HEADS 12
#define HEAD_DIM 64
#define EMB 768
#define SEQ 4096
#define BATCH 2
#define ROWS (BATCH*SEQ)     // 8192
#define DQKV (3*EMB)         // 2304

typedef __attribute__((ext_vector_type(8))) __bf16 bf16x8;
typedef __attribute__((ext_vector_type(4))) float floatx4;

static __device__ __forceinline__ unsigned short f2bf(float f) {
  unsigned int u = __float_as_uint(f);
  u += 0x7FFFu + ((u >> 16) & 1u);          // round-to-nearest-even
  return (unsigned short)(u >> 16);
}

static __device__ __forceinline__ float bf2f(unsigned short h) {
  return __uint_as_float(((unsigned int)h) << 16);
}

// truncating pack: two fp32 -> bf16x2 dword {hi(b),hi(a)} — 1 v_perm, no adds
static __device__ __forceinline__ unsigned int pack_bf2_trunc(float a, float b) {
  return __builtin_amdgcn_perm(__float_as_uint(b), __float_as_uint(a), 0x07060302u);
}

static __device__ __forceinline__ void async_cp16(void* lds, const void* g) {
  __builtin_amdgcn_global_load_lds(
      (__attribute__((address_space(1))) void*)(g),
      (__attribute__((address_space(3))) void*)(lds), 16, 0, 0);
}

// key permutation within a 32-key group: PV lane (quad fq) reads its 8 keys
// {4fq+0..3, 16+4fq+0..3} as ONE contiguous 16B chunk (conflict-free b128).
static __device__ __forceinline__ int perm_key(int nn) {
  return (nn & ~31) | (((nn >> 2) & 3) * 8 + ((nn >> 4) & 1) * 4 + (nn & 3));
}

// ---------------- fp32 -> bf16 convert (x and w fused) ----------------
#define N4X (ROWS*EMB/4)
#define N4W (DQKV*EMB/4)
__global__ __launch_bounds__(256) void cvt2_kernel(
    const float* __restrict__ x, const float* __restrict__ w,
    unsigned short* __restrict__ xb, unsigned short* __restrict__ wb) {
  int i = blockIdx.x * blockDim.x + threadIdx.x;
  const float4* src;
  ushort4* dst;
  if (i < N4X) { src = (const float4*)x; dst = (ushort4*)xb; }
  else { i -= N4X; if (i >= N4W) return; src = (const float4*)w; dst = (ushort4*)wb; }
  float4 v = src[i];
  ushort4 o;
  o.x = f2bf(v.x); o.y = f2bf(v.y); o.z = f2bf(v.z); o.w = f2bf(v.w);
  dst[i] = o;
}

// ---------------- unified QKV projection GEMM (unchanged) --------
__global__ __launch_bounds__(256) void qkv_gemm_kernel(
    const unsigned short* __restrict__ xb, const unsigned short* __restrict__ wb,
    const float* __restrict__ bias,
    unsigned short* __restrict__ Qb, unsigned short* __restrict__ Kb,
    unsigned short* __restrict__ Vt) {
  __shared__ unsigned short As[128 * 64];
  __shared__ unsigned short Bs[128 * 64];
  const int t = threadIdx.x;
  const int lane = t & 63;
  const int w = t >> 6;
  const int wm = w >> 1, wn = w & 1;
  const int fr = lane & 15, fq = lane >> 4;
  const int fx = fr & 7;
  const int m0 = blockIdx.x * 128;
  const int n0 = blockIdx.y * 128;
  const int sel = n0 / EMB;       // 0=Q 1=K 2=V (block-uniform)
  const int lr = t >> 3;          // 0..31
  const int sc = t & 7;           // chunk col 0..7

  floatx4 acc[4][4];
#pragma unroll
  for (int i = 0; i < 4; ++i)
#pragma unroll
    for (int j = 0; j < 4; ++j) acc[i][j] = (floatx4)(0.0f);

  if (sel < 2) {
    for (int k0 = 0; k0 < EMB; k0 += 64) {
      __syncthreads();
#pragma unroll
      for (int i = 0; i < 4; ++i) {
        const int rr = i*32 + lr;
        const int cg = ((sc ^ (lr & 7)) * 8);
        async_cp16(&As[rr*64 + sc*8], &xb[(size_t)(m0 + rr)*EMB + k0 + cg]);
        async_cp16(&Bs[rr*64 + sc*8], &wb[(size_t)(n0 + rr)*EMB + k0 + cg]);
      }
      __syncthreads();
#pragma unroll
      for (int ks = 0; ks < 2; ++ks) {
        bf16x8 af[4], bfr[4];
#pragma unroll
        for (int i = 0; i < 4; ++i)
          af[i] = *(const bf16x8*)&As[(wm*64 + i*16 + fr)*64 + (((ks*4+fq) ^ fx)*8)];
#pragma unroll
        for (int j = 0; j < 4; ++j)
          bfr[j] = *(const bf16x8*)&Bs[(wn*64 + j*16 + fr)*64 + (((ks*4+fq) ^ fx)*8)];
#pragma unroll
        for (int i = 0; i < 4; ++i)
#pragma unroll
          for (int j = 0; j < 4; ++j)
            acc[i][j] = __builtin_amdgcn_mfma_f32_16x16x32_bf16(bfr[j], af[i], acc[i][j], 0, 0, 0);
      }
    }
    // D layout: row (feature) = j*16 + fq*4 + reg, col (x row) = i*16 + fr.
    const float qscale = 0.125f * 1.4426950408889634f;  // 1/sqrt(64)*log2(e)
    const float sc2 = (sel == 0) ? qscale : 1.0f;
    unsigned short* dst = (sel == 0) ? Qb : Kb;
#pragma unroll
    for (int i = 0; i < 4; ++i) {
      const int mr = m0 + wm*64 + i*16 + fr;      // x row
      const int b = mr / SEQ;
      const int nn = mr - b*SEQ;
#pragma unroll
      for (int j = 0; j < 4; ++j) {
        const int og = n0 + wn*64 + j*16 + fq*4;  // feature base (4 consecutive)
        const int oo = og - sel*EMB;
        const int hh = oo >> 6, dd = oo & 63;
        const float4 bv = *(const float4*)&bias[og];
        ushort4 pk;
        pk.x = f2bf((acc[i][j][0] + bv.x) * sc2);
        pk.y = f2bf((acc[i][j][1] + bv.y) * sc2);
        pk.z = f2bf((acc[i][j][2] + bv.z) * sc2);
        pk.w = f2bf((acc[i][j][3] + bv.w) * sc2);
        *(ushort4*)&dst[(((size_t)(b*NUM_HEADS + hh))*SEQ + nn)*HEAD_DIM + dd] = pk;
      }
    }
  } else {
    for (int k0 = 0; k0 < EMB; k0 += 64) {
      __syncthreads();
#pragma unroll
      for (int i = 0; i < 4; ++i) {
        const int rr = i*32 + lr;
        const int cg = ((sc ^ (lr & 7)) * 8);
        async_cp16(&As[rr*64 + sc*8], &xb[(size_t)(m0 + rr)*EMB + k0 + cg]);
        async_cp16(&Bs[rr*64 + sc*8], &wb[(size_t)(n0 + rr)*EMB + k0 + cg]);
      }
      __syncthreads();
#pragma unroll
      for (int ks = 0; ks < 2; ++ks) {
        bf16x8 af[4], bfr[4];
#pragma unroll
        for (int i = 0; i < 4; ++i)
          af[i] = *(const bf16x8*)&As[(wm*64 + i*16 + fr)*64 + (((ks*4+fq) ^ fx)*8)];
#pragma unroll
        for (int j = 0; j < 4; ++j)
          bfr[j] = *(const bf16x8*)&Bs[(wn*64 + j*16 + fr)*64 + (((ks*4+fq) ^ fx)*8)];
#pragma unroll
        for (int i = 0; i < 4; ++i)
#pragma unroll
          for (int j = 0; j < 4; ++j)
            acc[i][j] = __builtin_amdgcn_mfma_f32_16x16x32_bf16(af[i], bfr[j], acc[i][j], 0, 0, 0);
      }
    }
    // D layout: row (x row) = i*16 + fq*4 + reg, col (feature) = j*16 + fr.
#pragma unroll
    for (int i = 0; i < 4; ++i) {
      const int mr = m0 + wm*64 + i*16 + fq*4;    // x row base (4 consecutive)
      const int b = mr / SEQ;
      const int nn = perm_key(mr - b*SEQ);        // key-permuted position
#pragma unroll
      for (int j = 0; j < 4; ++j) {
        const int feat = n0 + wn*64 + j*16 + fr;
        const int oo = feat - 2*EMB;
        const int hh = oo >> 6, dd = oo & 63;
        const float bv = bias[feat];
        ushort4 pk;
        pk.x = f2bf(acc[i][j][0] + bv);
        pk.y = f2bf(acc[i][j][1] + bv);
        pk.z = f2bf(acc[i][j][2] + bv);
        pk.w = f2bf(acc[i][j][3] + bv);
        *(ushort4*)&Vt[(((size_t)(b*NUM_HEADS + hh))*HEAD_DIM + dd)*SEQ + nn] = pk;
      }
    }
  }
}

// ---------------- flash attention: split-K, 4 waves x 64 q-rows --------------
// grid (SEQ/256, BATCH*NUM_HEADS, 2): blockIdx.z = key-half. Block = 256 q-rows
// x 2048 keys, 4 waves of 64 q-rows each. Writes UNNORMALIZED partial O (f32)
// + partial row-sum l; ln_kernel merges exactly (no running max -> exact).
// Rationale chain (R2/R3 measurements): 64q/wave is 1.42x more efficient per
// wave-slot than 32q (half the LDS fragment reads, 4 g-streams of MFMA ILP);
// residency is capped at ~2.5 BLOCKS/CU (not waves) by the LDS allocator, so
// waves/CU = blocks-cap x waves/block -> must use 4-wave blocks. This geometry
// (256 thr, 32 KB, 768 blocks) measured 8.6 waves/CU in R0.
#define NKH (SEQ/2)          // keys per half = 2048
#define NTH (NKH/64)         // 32 tiles per half
__global__ __launch_bounds__(256, 2) void attn_kernel(
    const unsigned short* __restrict__ Qb, const unsigned short* __restrict__ Kb,
    const unsigned short* __restrict__ Vt,
    float* __restrict__ Opart, float* __restrict__ lpart) {
  __shared__ unsigned short Ks[2][64 * 64];   // [buf][key][d], swizzled chunks
  __shared__ unsigned short Vs[2][64 * 64];   // [buf][d][perm key], swizzled
  const int t = threadIdx.x;
  const int lane = t & 63;
  const int w = t >> 6;                     // 0..3
  const int fr = lane & 15, fq = lane >> 4;
  const int fx = fr & 7;
  const int bh = blockIdx.y;
  const int half = blockIdx.z;
  const int kc0 = half * NKH;
  const int q0 = blockIdx.x * 256 + w * 64;

  // Q fragments (B-operand of S^T): per q-group g, rows q0+g*16+fr.
  bf16x8 aq[4][2];
#pragma unroll
  for (int g = 0; g < 4; ++g) {
    const size_t qoff = ((size_t)bh * SEQ + q0 + g*16 + fr) * HEAD_DIM;
    aq[g][0] = *(const bf16x8*)&Qb[qoff + fq*8];
    aq[g][1] = *(const bf16x8*)&Qb[qoff + 32 + fq*8];
  }

  union { unsigned int u[4]; bf16x8 b; } onesu;
  onesu.u[0] = onesu.u[1] = onesu.u[2] = onesu.u[3] = 0x3F803F80u;
  const bf16x8 onesb = onesu.b;

  floatx4 o[4][4];
  floatx4 lsum[4];
#pragma unroll
  for (int g = 0; g < 4; ++g) {
    lsum[g] = (floatx4)(0.f);
#pragma unroll
    for (int d = 0; d < 4; ++d) o[g][d] = (floatx4)(0.f);
  }

  const size_t kb = (size_t)bh * SEQ * HEAD_DIM;
  const size_t vb = (size_t)bh * HEAD_DIM * SEQ;

  // stage one 64-key tile: 8KB K + 8KB V = 1024 chunks / 256 thr = 4 cp16/thr
  auto stage = [&](int kc, int bi) {
#pragma unroll
    for (int i = 0; i < 2; ++i) {
      const int chunk = i*256 + t;
      const int r = chunk >> 3, c = chunk & 7;
      async_cp16(&Ks[bi][chunk*8], &Kb[kb + (size_t)(kc + r)*HEAD_DIM + ((c ^ (r&7))*8)]);
    }
#pragma unroll
    for (int i = 0; i < 2; ++i) {
      const int chunk = i*256 + t;
      const int r = chunk >> 3, c = chunk & 7;
      async_cp16(&Vs[bi][chunk*8], &Vt[vb + (size_t)r*SEQ + kc + ((c ^ (r&7))*8)]);
    }
  };

  // one 32-key chunk J of the current 64-key tile
  auto chunk_compute = [&](const unsigned short* ksp, const unsigned short* vsp,
                           int J) {
    // S^T fragments: 16 MFMAs off 4 ds_reads (k0/k1 shared across all 4 g)
    floatx4 z[4][2];
#pragma unroll
    for (int jj = 0; jj < 2; ++jj) {
      const int row = (J*2 + jj)*16 + fr;   // key row in tile
      bf16x8 k0 = *(const bf16x8*)&ksp[row*64 + ((fq ^ fx)*8)];
      bf16x8 k1 = *(const bf16x8*)&ksp[row*64 + (((fq+4) ^ fx)*8)];
#pragma unroll
      for (int g = 0; g < 4; ++g) {
        floatx4 a = (floatx4)(0.f);
        a = __builtin_amdgcn_mfma_f32_16x16x32_bf16(k0, aq[g][0], a, 0, 0, 0);
        a = __builtin_amdgcn_mfma_f32_16x16x32_bf16(k1, aq[g][1], a, 0, 0, 0);
        z[g][jj] = a;                       // S^T: key=16(2J+jj)+fq*4+r, q=fr
      }
    }
    // V fragments once per chunk, shared across g (4 ds_reads)
    bf16x8 vvb[4];
    const int vc = ((4*J + fq) ^ fx) * 8;
#pragma unroll
    for (int dt = 0; dt < 4; ++dt)
      vvb[dt] = *(const bf16x8*)&vsp[(dt*16 + fr)*64 + vc];
    // per-g softmax + lsum + PV: exp2 of g overlaps MFMAs of g-1
#pragma unroll
    for (int g = 0; g < 4; ++g) {
      float e0 = __builtin_amdgcn_exp2f(z[g][0][0]);
      float e1 = __builtin_amdgcn_exp2f(z[g][0][1]);
      float e2 = __builtin_amdgcn_exp2f(z[g][0][2]);
      float e3 = __builtin_amdgcn_exp2f(z[g][0][3]);
      float e4 = __builtin_amdgcn_exp2f(z[g][1][0]);
      float e5 = __builtin_amdgcn_exp2f(z[g][1][1]);
      float e6 = __builtin_amdgcn_exp2f(z[g][1][2]);
      float e7 = __builtin_amdgcn_exp2f(z[g][1][3]);
      union { unsigned int u[4]; bf16x8 b; } cv;
      cv.u[0] = pack_bf2_trunc(e0, e1);
      cv.u[1] = pack_bf2_trunc(e2, e3);
      cv.u[2] = pack_bf2_trunc(e4, e5);
      cv.u[3] = pack_bf2_trunc(e6, e7);
      const bf16x8 ap = cv.b;
      __builtin_amdgcn_s_setprio(1);
      lsum[g] = __builtin_amdgcn_mfma_f32_16x16x32_bf16(ap, onesb, lsum[g], 0, 0, 0);
#pragma unroll
      for (int dt = 0; dt < 4; ++dt)
        o[g][dt] = __builtin_amdgcn_mfma_f32_16x16x32_bf16(ap, vvb[dt], o[g][dt], 0, 0, 0);
      __builtin_amdgcn_s_setprio(0);
    }
  };

  // prologue: prefetch tiles 0 and 1, wait tile 0 only (tile 1 stays in flight)
  stage(kc0, 0);
  stage(kc0 + 64, 1);
  asm volatile("s_waitcnt vmcnt(4)" ::: "memory");
  __builtin_amdgcn_s_barrier();

  int cur = 0;
  for (int tt = 0; tt < NTH; ++tt) {
    const unsigned short* ksp = Ks[cur];
    const unsigned short* vsp = Vs[cur];
    chunk_compute(ksp, vsp, 0);
    chunk_compute(ksp, vsp, 1);
    if (tt == NTH - 1) break;
    __builtin_amdgcn_s_barrier();    // all waves done reading buf[cur]
    if (tt + 2 < NTH) {
      stage(kc0 + (tt + 2) * 64, cur);  // refill the buffer we just finished
      asm volatile("s_waitcnt vmcnt(4)" ::: "memory");  // tile tt+1 landed
    } else {
      asm volatile("s_waitcnt vmcnt(0)" ::: "memory");  // drain final tile
    }
    __builtin_amdgcn_s_barrier();    // tile tt+1 visible to all waves
    cur ^= 1;
  }

  // epilogue: write unnormalized partial O (f32) + partial row-sum l
  const size_t pb = (size_t)(half * BATCH * NUM_HEADS + bh);
  const size_t obase = pb * SEQ * HEAD_DIM;
  const size_t lbase = pb * SEQ;
#pragma unroll
  for (int g = 0; g < 4; ++g) {
#pragma unroll
    for (int r4 = 0; r4 < 4; ++r4) {
      const int q = q0 + g*16 + fq*4 + r4;
      float* op = &Opart[obase + (size_t)q * HEAD_DIM];
#pragma unroll
      for (int dt = 0; dt < 4; ++dt)
        op[dt*16 + fr] = o[g][dt][r4];
      if (fr == 0) lpart[lbase + q] = lsum[g][r4];
    }
  }
}

// ---------- residual + split-K merge + LayerNorm: one wave per row ----------
__global__ __launch_bounds__(256) void ln_kernel(
    const float* __restrict__ x,
    const float* __restrict__ Opart, const float* __restrict__ lpart,
    const float* __restrict__ gamma, const float* __restrict__ beta,
    float* __restrict__ out) {
  const int row = blockIdx.x * 4 + (threadIdx.x >> 6);  // global row b*SEQ+n
  const int lane = threadIdx.x & 63;
  const int b = row >> 12;              // / SEQ
  const int n = row & (SEQ - 1);
  const size_t base = (size_t)row * EMB;
  const size_t HSTRIDE = (size_t)BATCH * NUM_HEADS * SEQ;   // half stride (l)
  const size_t HOSTRIDE = HSTRIDE * HEAD_DIM;               // half stride (O)
  float4 v[3];
  float s = 0.f, s2 = 0.f;
#pragma unroll
  for (int k = 0; k < 3; ++k) {
    const int c = lane*4 + k*256;
    const int h = c >> 6, d4 = c & 63;
    const size_t oi = (((size_t)(b*NUM_HEADS + h))*SEQ + n)*HEAD_DIM + d4;
    const size_t li = ((size_t)(b*NUM_HEADS + h))*SEQ + n;
    const float4 p0 = *(const float4*)&Opart[oi];
    const float4 p1 = *(const float4*)&Opart[oi + HOSTRIDE];
    const float rl = 1.0f / (lpart[li] + lpart[li + HSTRIDE]);
    const float4 xv = *(const float4*)&x[base + c];
    v[k].x = xv.x + (p0.x + p1.x) * rl;
    v[k].y = xv.y + (p0.y + p1.y) * rl;
    v[k].z = xv.z + (p0.z + p1.z) * rl;
    v[k].w = xv.w + (p0.w + p1.w) * rl;
    s  += (v[k].x + v[k].y) + (v[k].z + v[k].w);
    s2 += (v[k].x*v[k].x + v[k].y*v[k].y) + (v[k].z*v[k].z + v[k].w*v[k].w);
  }
#pragma unroll
  for (int off = 1; off < 64; off <<= 1) {
    s  += __shfl_xor(s,  off);
    s2 += __shfl_xor(s2, off);
  }
  const float mean = s * (1.0f / EMB);
  const float var  = s2 * (1.0f / EMB) - mean * mean;
  const float rstd = rsqrtf(var + 1e-5f);
#pragma unroll
  for (int k = 0; k < 3; ++k) {
    const int c = lane*4 + k*256;
    const float4 g4 = *(const float4*)&gamma[c];
    const float4 b4 = *(const float4*)&beta[c];
    float4 ov;
    ov.x = (v[k].x - mean) * rstd * g4.x + b4.x;
    ov.y = (v[k].y - mean) * rstd * g4.y + b4.y;
    ov.z = (v[k].z - mean) * rstd * g4.z + b4.z;
    ov.w = (v[k].w - mean) * rstd * g4.w + b4.w;
    *(float4*)&out[base + c] = ov;
  }
}

extern "C" void kernel_launch(void* const* d_in, const int* in_sizes, int n_in,
                              void* d_out, int out_size, void* d_ws, size_t ws_size,
                              hipStream_t stream) {
  const float* x      = (const float*)d_in[0];
  const float* w_qkv  = (const float*)d_in[1];
  const float* b_qkv  = (const float*)d_in[2];
  const float* gamma  = (const float*)d_in[3];
  const float* beta   = (const float*)d_in[4];
  float* out = (float*)d_out;

  unsigned short* xb = (unsigned short*)d_ws;                 // 8192*768 bf16
  unsigned short* wb = xb + (size_t)ROWS * EMB;               // 2304*768 bf16
  unsigned short* Qb = wb + (size_t)DQKV * EMB;               // [b,h,n,64] bf16 (scaled)
  unsigned short* Kb = Qb + (size_t)ROWS * EMB;               // [b,h,n,64] bf16
  unsigned short* Vt = Kb + (size_t)ROWS * EMB;               // [b,h,64,perm n] bf16
  float* Opart = (float*)(Vt + (size_t)ROWS * EMB);           // [2,b,h,n,64] f32
  float* lpart = Opart + (size_t)2 * ROWS * EMB;              // [2,b,h,n] f32

  cvt2_kernel<<<(N4X + N4W + 255)/256, 256, 0, stream>>>(x, w_qkv, xb, wb);
  qkv_gemm_kernel<<<dim3(ROWS/128, DQKV/128), 256, 0, stream>>>(xb, wb, b_qkv, Qb, Kb, Vt);
  attn_kernel<<<dim3(SEQ/256, BATCH*NUM_HEADS, 2), 256, 0, stream>>>(Qb, Kb, Vt, Opart, lpart);
  ln_kernel<<<ROWS/4, 256, 0, stream>>>(x, Opart, lpart, gamma, beta, out);
}

// Round 6
// 249.327 us; speedup vs baseline: 1.1169x; 1.0246x over previous
//
#include <hip/hip_runtime.h>
#include <stdint.h>

#define NUM_HEADS 12
#define HEAD_DIM 64
#define EMB 768
#define SEQ 4096
#define BATCH 2
#define ROWS (BATCH*SEQ)     // 8192
#define DQKV (3*EMB)         // 2304

typedef __attribute__((ext_vector_type(8))) __bf16 bf16x8;
typedef __attribute__((ext_vector_type(4))) float floatx4;

static __device__ __forceinline__ unsigned short f2bf(float f) {
  unsigned int u = __float_as_uint(f);
  u += 0x7FFFu + ((u >> 16) & 1u);          // round-to-nearest-even
  return (unsigned short)(u >> 16);
}

static __device__ __forceinline__ float bf2f(unsigned short h) {
  return __uint_as_float(((unsigned int)h) << 16);
}

// truncating pack: two fp32 -> bf16x2 dword {hi(b),hi(a)} — 1 v_perm, no adds
static __device__ __forceinline__ unsigned int pack_bf2_trunc(float a, float b) {
  return __builtin_amdgcn_perm(__float_as_uint(b), __float_as_uint(a), 0x07060302u);
}

static __device__ __forceinline__ void async_cp16(void* lds, const void* g) {
  __builtin_amdgcn_global_load_lds(
      (__attribute__((address_space(1))) void*)(g),
      (__attribute__((address_space(3))) void*)(lds), 16, 0, 0);
}

// key permutation within a 32-key group: PV lane (quad fq) reads its 8 keys
// {4fq+0..3, 16+4fq+0..3} as ONE contiguous 16B chunk (conflict-free b128).
static __device__ __forceinline__ int perm_key(int nn) {
  return (nn & ~31) | (((nn >> 2) & 3) * 8 + ((nn >> 4) & 1) * 4 + (nn & 3));
}

// ---------------- fp32 -> bf16 convert (x and w fused) ----------------
#define N4X (ROWS*EMB/4)
#define N4W (DQKV*EMB/4)
__global__ __launch_bounds__(256) void cvt2_kernel(
    const float* __restrict__ x, const float* __restrict__ w,
    unsigned short* __restrict__ xb, unsigned short* __restrict__ wb) {
  int i = blockIdx.x * blockDim.x + threadIdx.x;
  const float4* src;
  ushort4* dst;
  if (i < N4X) { src = (const float4*)x; dst = (ushort4*)xb; }
  else { i -= N4X; if (i >= N4W) return; src = (const float4*)w; dst = (ushort4*)wb; }
  float4 v = src[i];
  ushort4 o;
  o.x = f2bf(v.x); o.y = f2bf(v.y); o.z = f2bf(v.z); o.w = f2bf(v.w);
  dst[i] = o;
}

// ---------------- unified QKV projection GEMM (unchanged) --------
__global__ __launch_bounds__(256) void qkv_gemm_kernel(
    const unsigned short* __restrict__ xb, const unsigned short* __restrict__ wb,
    const float* __restrict__ bias,
    unsigned short* __restrict__ Qb, unsigned short* __restrict__ Kb,
    unsigned short* __restrict__ Vt) {
  __shared__ unsigned short As[128 * 64];
  __shared__ unsigned short Bs[128 * 64];
  const int t = threadIdx.x;
  const int lane = t & 63;
  const int w = t >> 6;
  const int wm = w >> 1, wn = w & 1;
  const int fr = lane & 15, fq = lane >> 4;
  const int fx = fr & 7;
  const int m0 = blockIdx.x * 128;
  const int n0 = blockIdx.y * 128;
  const int sel = n0 / EMB;       // 0=Q 1=K 2=V (block-uniform)
  const int lr = t >> 3;          // 0..31
  const int sc = t & 7;           // chunk col 0..7

  floatx4 acc[4][4];
#pragma unroll
  for (int i = 0; i < 4; ++i)
#pragma unroll
    for (int j = 0; j < 4; ++j) acc[i][j] = (floatx4)(0.0f);

  if (sel < 2) {
    for (int k0 = 0; k0 < EMB; k0 += 64) {
      __syncthreads();
#pragma unroll
      for (int i = 0; i < 4; ++i) {
        const int rr = i*32 + lr;
        const int cg = ((sc ^ (lr & 7)) * 8);
        async_cp16(&As[rr*64 + sc*8], &xb[(size_t)(m0 + rr)*EMB + k0 + cg]);
        async_cp16(&Bs[rr*64 + sc*8], &wb[(size_t)(n0 + rr)*EMB + k0 + cg]);
      }
      __syncthreads();
#pragma unroll
      for (int ks = 0; ks < 2; ++ks) {
        bf16x8 af[4], bfr[4];
#pragma unroll
        for (int i = 0; i < 4; ++i)
          af[i] = *(const bf16x8*)&As[(wm*64 + i*16 + fr)*64 + (((ks*4+fq) ^ fx)*8)];
#pragma unroll
        for (int j = 0; j < 4; ++j)
          bfr[j] = *(const bf16x8*)&Bs[(wn*64 + j*16 + fr)*64 + (((ks*4+fq) ^ fx)*8)];
#pragma unroll
        for (int i = 0; i < 4; ++i)
#pragma unroll
          for (int j = 0; j < 4; ++j)
            acc[i][j] = __builtin_amdgcn_mfma_f32_16x16x32_bf16(bfr[j], af[i], acc[i][j], 0, 0, 0);
      }
    }
    // D layout: row (feature) = j*16 + fq*4 + reg, col (x row) = i*16 + fr.
    const float qscale = 0.125f * 1.4426950408889634f;  // 1/sqrt(64)*log2(e)
    const float sc2 = (sel == 0) ? qscale : 1.0f;
    unsigned short* dst = (sel == 0) ? Qb : Kb;
#pragma unroll
    for (int i = 0; i < 4; ++i) {
      const int mr = m0 + wm*64 + i*16 + fr;      // x row
      const int b = mr / SEQ;
      const int nn = mr - b*SEQ;
#pragma unroll
      for (int j = 0; j < 4; ++j) {
        const int og = n0 + wn*64 + j*16 + fq*4;  // feature base (4 consecutive)
        const int oo = og - sel*EMB;
        const int hh = oo >> 6, dd = oo & 63;
        const float4 bv = *(const float4*)&bias[og];
        ushort4 pk;
        pk.x = f2bf((acc[i][j][0] + bv.x) * sc2);
        pk.y = f2bf((acc[i][j][1] + bv.y) * sc2);
        pk.z = f2bf((acc[i][j][2] + bv.z) * sc2);
        pk.w = f2bf((acc[i][j][3] + bv.w) * sc2);
        *(ushort4*)&dst[(((size_t)(b*NUM_HEADS + hh))*SEQ + nn)*HEAD_DIM + dd] = pk;
      }
    }
  } else {
    for (int k0 = 0; k0 < EMB; k0 += 64) {
      __syncthreads();
#pragma unroll
      for (int i = 0; i < 4; ++i) {
        const int rr = i*32 + lr;
        const int cg = ((sc ^ (lr & 7)) * 8);
        async_cp16(&As[rr*64 + sc*8], &xb[(size_t)(m0 + rr)*EMB + k0 + cg]);
        async_cp16(&Bs[rr*64 + sc*8], &wb[(size_t)(n0 + rr)*EMB + k0 + cg]);
      }
      __syncthreads();
#pragma unroll
      for (int ks = 0; ks < 2; ++ks) {
        bf16x8 af[4], bfr[4];
#pragma unroll
        for (int i = 0; i < 4; ++i)
          af[i] = *(const bf16x8*)&As[(wm*64 + i*16 + fr)*64 + (((ks*4+fq) ^ fx)*8)];
#pragma unroll
        for (int j = 0; j < 4; ++j)
          bfr[j] = *(const bf16x8*)&Bs[(wn*64 + j*16 + fr)*64 + (((ks*4+fq) ^ fx)*8)];
#pragma unroll
        for (int i = 0; i < 4; ++i)
#pragma unroll
          for (int j = 0; j < 4; ++j)
            acc[i][j] = __builtin_amdgcn_mfma_f32_16x16x32_bf16(af[i], bfr[j], acc[i][j], 0, 0, 0);
      }
    }
    // D layout: row (x row) = i*16 + fq*4 + reg, col (feature) = j*16 + fr.
#pragma unroll
    for (int i = 0; i < 4; ++i) {
      const int mr = m0 + wm*64 + i*16 + fq*4;    // x row base (4 consecutive)
      const int b = mr / SEQ;
      const int nn = perm_key(mr - b*SEQ);        // key-permuted position
#pragma unroll
      for (int j = 0; j < 4; ++j) {
        const int feat = n0 + wn*64 + j*16 + fr;
        const int oo = feat - 2*EMB;
        const int hh = oo >> 6, dd = oo & 63;
        const float bv = bias[feat];
        ushort4 pk;
        pk.x = f2bf(acc[i][j][0] + bv);
        pk.y = f2bf(acc[i][j][1] + bv);
        pk.z = f2bf(acc[i][j][2] + bv);
        pk.w = f2bf(acc[i][j][3] + bv);
        *(ushort4*)&Vt[(((size_t)(b*NUM_HEADS + hh))*HEAD_DIM + dd)*SEQ + nn] = pk;
      }
    }
  }
}

// ---------------- flash attention: R0 body + split-K=2 -----------------------
// grid (SEQ/128, BATCH*NUM_HEADS, 2), 256 thr = 4 waves x 32 q-rows. Each block
// does 128 q-rows x 2048 keys, writes UNNORMALIZED partial O (f32) + partial
// row-sum l; ln merges exactly: att = (O0+O1)/(l0+l1) (no running max).
// Rationale (R5 measurement): grid was the residency cap — 768 blocks = exactly
// 3/CU of work, avg ~2.2 resident; barrier-locked waves in one block share a
// phase, so MFMA (42%) and VALU (39%) alternated instead of overlapping.
// Split-K doubles block supply to 6/CU (LDS allows 5 resident): independent
// blocks provide out-of-phase streams so the two pipes overlap (m114).
// Inner structure byte-identical to the measured-110us R0 kernel.
#define NKH (SEQ/2)          // keys per half = 2048
__global__ __launch_bounds__(256, 4) void attn_kernel(
    const unsigned short* __restrict__ Qb, const unsigned short* __restrict__ Kb,
    const unsigned short* __restrict__ Vt,
    float* __restrict__ Opart, float* __restrict__ lpart) {
  __shared__ unsigned short Ks[128 * 64];     // [key][d], 8 chunks/row, swizzled
  __shared__ unsigned short Vs[2][64 * 64];   // [half][d][perm key], 8 chunks/row
  const int t = threadIdx.x;
  const int lane = t & 63;
  const int w = t >> 6;                     // 0..3
  const int fr = lane & 15, fq = lane >> 4;
  const int fx = fr & 7;
  const int bh = blockIdx.y;
  const int half = blockIdx.z;
  const int kc0 = half * NKH;
  const int q0 = blockIdx.x * 128 + w * 32;

  // Q fragments (B-operand of S^T): per q-group g, rows q0+g*16+fr.
  bf16x8 aq[2][2];
#pragma unroll
  for (int g = 0; g < 2; ++g) {
    const size_t qoff = ((size_t)bh * SEQ + q0 + g*16 + fr) * HEAD_DIM;
    aq[g][0] = *(const bf16x8*)&Qb[qoff + fq*8];
    aq[g][1] = *(const bf16x8*)&Qb[qoff + 32 + fq*8];
  }

  union { unsigned int u[4]; bf16x8 b; } onesu;
  onesu.u[0] = onesu.u[1] = onesu.u[2] = onesu.u[3] = 0x3F803F80u;
  const bf16x8 onesb = onesu.b;

  floatx4 o[2][4];
  floatx4 lsum[2];
#pragma unroll
  for (int g = 0; g < 2; ++g) {
    lsum[g] = (floatx4)(0.f);
#pragma unroll
    for (int d = 0; d < 4; ++d) o[g][d] = (floatx4)(0.f);
  }

  const size_t kb = (size_t)bh * SEQ * HEAD_DIM;
  const size_t vb = (size_t)bh * HEAD_DIM * SEQ;

  // S^T fragments for one 32-key chunk: 8 MFMAs, depends only on Ks.
  auto sfrag = [&](int J2, floatx4 (&zz)[2][2]) {
#pragma unroll
    for (int jj = 0; jj < 2; ++jj) {
      const int row = (J2*2 + jj)*16 + fr;  // key row in Ks
      bf16x8 k0 = *(const bf16x8*)&Ks[row*64 + ((fq ^ fx)*8)];
      bf16x8 k1 = *(const bf16x8*)&Ks[row*64 + (((fq+4) ^ fx)*8)];
#pragma unroll
      for (int g = 0; g < 2; ++g) {
        floatx4 a = (floatx4)(0.f);
        a = __builtin_amdgcn_mfma_f32_16x16x32_bf16(k0, aq[g][0], a, 0, 0, 0);
        a = __builtin_amdgcn_mfma_f32_16x16x32_bf16(k1, aq[g][1], a, 0, 0, 0);
        zz[g][jj] = a;                      // S^T: key=16(2J+jj)+fq*4+r, q=fr
      }
    }
  };

  for (int kc = kc0; kc < kc0 + NKH; kc += 128) {
    __syncthreads();
#pragma unroll
    for (int i = 0; i < 4; ++i) {           // Ks: 1024 chunks, rows of 8
      const int chunk = i*256 + t;
      const int r = chunk >> 3, c = chunk & 7;
      async_cp16(&Ks[chunk*8], &Kb[kb + (size_t)(kc + r)*HEAD_DIM + ((c ^ (r&7))*8)]);
    }
#pragma unroll
    for (int i = 0; i < 4; ++i) {           // Vs: 2 halves x 512 chunks, rows of 8
      const int chunk = i*256 + t;
      const int h = chunk >> 9, rem = chunk & 511;
      const int r = rem >> 3, c = rem & 7;
      async_cp16(&Vs[0][0] + chunk*8,
                 &Vt[vb + (size_t)r*SEQ + kc + h*64 + ((c ^ (r&7))*8)]);
    }
    __syncthreads();

    floatx4 z[2][2];
    sfrag(0, z);
#pragma unroll
    for (int J = 0; J < 4; ++J) {           // 32-key chunks, pipelined
      floatx4 zn[2][2];
      if (J < 3) sfrag(J+1, zn);            // next chunk's S-MFMAs: in-flight
                                            // during this chunk's exp2 burst
      bf16x8 ap[2];
#pragma unroll
      for (int g = 0; g < 2; ++g) {
        float e0 = __builtin_amdgcn_exp2f(z[g][0][0]);
        float e1 = __builtin_amdgcn_exp2f(z[g][0][1]);
        float e2 = __builtin_amdgcn_exp2f(z[g][0][2]);
        float e3 = __builtin_amdgcn_exp2f(z[g][0][3]);
        float e4 = __builtin_amdgcn_exp2f(z[g][1][0]);
        float e5 = __builtin_amdgcn_exp2f(z[g][1][1]);
        float e6 = __builtin_amdgcn_exp2f(z[g][1][2]);
        float e7 = __builtin_amdgcn_exp2f(z[g][1][3]);
        union { unsigned int u[4]; bf16x8 b; } cv;
        cv.u[0] = pack_bf2_trunc(e0, e1);
        cv.u[1] = pack_bf2_trunc(e2, e3);
        cv.u[2] = pack_bf2_trunc(e4, e5);
        cv.u[3] = pack_bf2_trunc(e6, e7);
        ap[g] = cv.b;
      }
      // l += P * ones  (row-sum on the MFMA pipe; D rows = q like O)
#pragma unroll
      for (int g = 0; g < 2; ++g)
        lsum[g] = __builtin_amdgcn_mfma_f32_16x16x32_bf16(ap[g], onesb, lsum[g], 0, 0, 0);
      // PV: O[q][d] += P[q][key] V[key][d] over keys [32J, 32J+32)
      const unsigned short* vsh = &Vs[J >> 1][0];
      const int vc = ((4*(J & 1) + fq) ^ fx) * 8;
#pragma unroll
      for (int dt = 0; dt < 4; ++dt) {
        const bf16x8 vvb = *(const bf16x8*)&vsh[(dt*16 + fr)*64 + vc];
#pragma unroll
        for (int g = 0; g < 2; ++g)
          o[g][dt] = __builtin_amdgcn_mfma_f32_16x16x32_bf16(ap[g], vvb, o[g][dt], 0, 0, 0);
      }
      if (J < 3) {
#pragma unroll
        for (int g = 0; g < 2; ++g)
#pragma unroll
          for (int jj = 0; jj < 2; ++jj) z[g][jj] = zn[g][jj];
      }
    }
  }

  // epilogue: write unnormalized partial O (f32) + partial row-sum l
  const size_t pb = (size_t)(half * BATCH * NUM_HEADS + bh);
  const size_t obase = pb * SEQ * HEAD_DIM;
  const size_t lbase = pb * SEQ;
#pragma unroll
  for (int g = 0; g < 2; ++g) {
#pragma unroll
    for (int r4 = 0; r4 < 4; ++r4) {
      const int q = q0 + g*16 + fq*4 + r4;    // l[q=fq*4+r4] — same layout as O
      float* op = &Opart[obase + (size_t)q * HEAD_DIM];
#pragma unroll
      for (int dt = 0; dt < 4; ++dt)
        op[dt*16 + fr] = o[g][dt][r4];
      if (fr == 0) lpart[lbase + q] = lsum[g][r4];
    }
  }
}

// ---------- residual + split-K merge + LayerNorm: one wave per row ----------
__global__ __launch_bounds__(256) void ln_kernel(
    const float* __restrict__ x,
    const float* __restrict__ Opart, const float* __restrict__ lpart,
    const float* __restrict__ gamma, const float* __restrict__ beta,
    float* __restrict__ out) {
  const int row = blockIdx.x * 4 + (threadIdx.x >> 6);  // global row b*SEQ+n
  const int lane = threadIdx.x & 63;
  const int b = row >> 12;              // / SEQ
  const int n = row & (SEQ - 1);
  const size_t base = (size_t)row * EMB;
  const size_t HSTRIDE = (size_t)BATCH * NUM_HEADS * SEQ;   // half stride (l)
  const size_t HOSTRIDE = HSTRIDE * HEAD_DIM;               // half stride (O)
  float4 v[3];
  float s = 0.f, s2 = 0.f;
#pragma unroll
  for (int k = 0; k < 3; ++k) {
    const int c = lane*4 + k*256;
    const int h = c >> 6, d4 = c & 63;
    const size_t oi = (((size_t)(b*NUM_HEADS + h))*SEQ + n)*HEAD_DIM + d4;
    const size_t li = ((size_t)(b*NUM_HEADS + h))*SEQ + n;
    const float4 p0 = *(const float4*)&Opart[oi];
    const float4 p1 = *(const float4*)&Opart[oi + HOSTRIDE];
    const float rl = 1.0f / (lpart[li] + lpart[li + HSTRIDE]);
    const float4 xv = *(const float4*)&x[base + c];
    v[k].x = xv.x + (p0.x + p1.x) * rl;
    v[k].y = xv.y + (p0.y + p1.y) * rl;
    v[k].z = xv.z + (p0.z + p1.z) * rl;
    v[k].w = xv.w + (p0.w + p1.w) * rl;
    s  += (v[k].x + v[k].y) + (v[k].z + v[k].w);
    s2 += (v[k].x*v[k].x + v[k].y*v[k].y) + (v[k].z*v[k].z + v[k].w*v[k].w);
  }
#pragma unroll
  for (int off = 1; off < 64; off <<= 1) {
    s  += __shfl_xor(s,  off);
    s2 += __shfl_xor(s2, off);
  }
  const float mean = s * (1.0f / EMB);
  const float var  = s2 * (1.0f / EMB) - mean * mean;
  const float rstd = rsqrtf(var + 1e-5f);
#pragma unroll
  for (int k = 0; k < 3; ++k) {
    const int c = lane*4 + k*256;
    const float4 g4 = *(const float4*)&gamma[c];
    const float4 b4 = *(const float4*)&beta[c];
    float4 ov;
    ov.x = (v[k].x - mean) * rstd * g4.x + b4.x;
    ov.y = (v[k].y - mean) * rstd * g4.y + b4.y;
    ov.z = (v[k].z - mean) * rstd * g4.z + b4.z;
    ov.w = (v[k].w - mean) * rstd * g4.w + b4.w;
    *(float4*)&out[base + c] = ov;
  }
}

extern "C" void kernel_launch(void* const* d_in, const int* in_sizes, int n_in,
                              void* d_out, int out_size, void* d_ws, size_t ws_size,
                              hipStream_t stream) {
  const float* x      = (const float*)d_in[0];
  const float* w_qkv  = (const float*)d_in[1];
  const float* b_qkv  = (const float*)d_in[2];
  const float* gamma  = (const float*)d_in[3];
  const float* beta   = (const float*)d_in[4];
  float* out = (float*)d_out;

  unsigned short* xb = (unsigned short*)d_ws;                 // 8192*768 bf16
  unsigned short* wb = xb + (size_t)ROWS * EMB;               // 2304*768 bf16
  unsigned short* Qb = wb + (size_t)DQKV * EMB;               // [b,h,n,64] bf16 (scaled)
  unsigned short* Kb = Qb + (size_t)ROWS * EMB;               // [b,h,n,64] bf16
  unsigned short* Vt = Kb + (size_t)ROWS * EMB;               // [b,h,64,perm n] bf16
  float* Opart = (float*)(Vt + (size_t)ROWS * EMB);           // [2,b,h,n,64] f32
  float* lpart = Opart + (size_t)2 * ROWS * EMB;              // [2,b,h,n] f32

  cvt2_kernel<<<(N4X + N4W + 255)/256, 256, 0, stream>>>(x, w_qkv, xb, wb);
  qkv_gemm_kernel<<<dim3(ROWS/128, DQKV/128), 256, 0, stream>>>(xb, wb, b_qkv, Qb, Kb, Vt);
  attn_kernel<<<dim3(SEQ/128, BATCH*NUM_HEADS, 2), 256, 0, stream>>>(Qb, Kb, Vt, Opart, lpart);
  ln_kernel<<<ROWS/4, 256, 0, stream>>>(x, Opart, lpart, gamma, beta, out);
}